// Round 8
// baseline (152.339 us; speedup 1.0000x reference)
//
#include <hip/hip_runtime.h>

typedef __attribute__((ext_vector_type(8))) short short8;
typedef __attribute__((ext_vector_type(4))) float floatx4;
typedef _Float16 half8 __attribute__((ext_vector_type(8)));
typedef _Float16 half4 __attribute__((ext_vector_type(4)));
typedef _Float16 half2v __attribute__((ext_vector_type(2)));

static __device__ __forceinline__ unsigned short f2bf(float x) {
    unsigned int u = __builtin_bit_cast(unsigned int, x);
    unsigned int r = (u + 0x7FFFu + ((u >> 16) & 1u)) >> 16;
    return (unsigned short)r;
}

// ------------------------------------------------------------------
// Phase A1: factorized GEMM (verbatim R7-verified math):
//   ud[i] = zd[i] @ W1[0:128]  + 0.5*b1   (10000 x 128, fp16)
//   us[j] = zs[j] @ W1[128:256] + 0.5*b1  (15000 x 128, fp16)
// ------------------------------------------------------------------
static __device__ void phase_gemm(
    int b, const float* __restrict__ zd, const float* __restrict__ zs,
    const float* __restrict__ W1, const float* __restrict__ b1,
    _Float16* __restrict__ ud, _Float16* __restrict__ us,
    int ndrows, int nsrows, int ntd)
{
    const int tid  = threadIdx.x;
    const int lane = tid & 63;
    const int wave = tid >> 6;
    const int wh   = wave >> 1;
    const int we   = wave & 1;
    const int l15  = lane & 15;
    const int quad = lane >> 4;

    const bool isD = (b < ntd);
    const float* __restrict__ z = isD ? zd : zs;
    _Float16* __restrict__ u = isD ? ud : us;
    const int nrows = isD ? ndrows : nsrows;
    const int m0    = (isD ? b : b - ntd) * 64;
    const int koff0 = isD ? 0 : 128;
    const int whbase = wh * 64;

    short8 wfrag[16];
    #pragma unroll
    for (int s = 0; s < 4; ++s)
        #pragma unroll
        for (int mt = 0; mt < 4; ++mt) {
            short8 t;
            #pragma unroll
            for (int j = 0; j < 8; ++j)
                t[j] = (short)f2bf(
                    W1[(size_t)(koff0 + s * 32 + quad * 8 + j) * 128 +
                       whbase + mt * 16 + l15]);
            wfrag[s * 4 + mt] = t;
        }

    floatx4 acc[2][4];
    #pragma unroll
    for (int mt = 0; mt < 4; ++mt) {
        floatx4 bb = *reinterpret_cast<const floatx4*>(&b1[whbase + mt * 16 + quad * 4]);
        bb *= 0.5f;
        acc[0][mt] = bb;
        acc[1][mt] = bb;
    }

    int rowi[2], rowc[2];
    #pragma unroll
    for (int et = 0; et < 2; ++et) {
        rowi[et] = m0 + we * 32 + et * 16 + l15;
        rowc[et] = rowi[et] < nrows ? rowi[et] : nrows - 1;
    }

    #pragma unroll
    for (int s = 0; s < 4; ++s) {
        short8 bf[2];
        #pragma unroll
        for (int et = 0; et < 2; ++et) {
            const float* src = &z[(size_t)rowc[et] * 128 + s * 32 + quad * 8];
            floatx4 lo = *reinterpret_cast<const floatx4*>(src);
            floatx4 hi = *reinterpret_cast<const floatx4*>(src + 4);
            short8 t;
            t[0] = (short)f2bf(lo[0]); t[1] = (short)f2bf(lo[1]);
            t[2] = (short)f2bf(lo[2]); t[3] = (short)f2bf(lo[3]);
            t[4] = (short)f2bf(hi[0]); t[5] = (short)f2bf(hi[1]);
            t[6] = (short)f2bf(hi[2]); t[7] = (short)f2bf(hi[3]);
            bf[et] = t;
        }
        #pragma unroll
        for (int et = 0; et < 2; ++et)
            #pragma unroll
            for (int mt = 0; mt < 4; ++mt)
                acc[et][mt] = __builtin_amdgcn_mfma_f32_16x16x32_bf16(
                    wfrag[s * 4 + mt], bf[et], acc[et][mt], 0, 0, 0);
    }

    #pragma unroll
    for (int et = 0; et < 2; ++et) {
        if (rowi[et] < nrows) {
            #pragma unroll
            for (int mt = 0; mt < 4; ++mt) {
                half4 hv;
                #pragma unroll
                for (int rr = 0; rr < 4; ++rr) hv[rr] = (_Float16)acc[et][mt][rr];
                *reinterpret_cast<half4*>(
                    &u[(size_t)rowi[et] * 128 + whbase + mt * 16 + quad * 4]) = hv;
            }
        }
    }
}

// ------------------------------------------------------------------
// Phase A2: LDS-aggregated histogram over bins = (col>=colh)*nbrow + (row>>4)
// ------------------------------------------------------------------
static __device__ void phase_hist(
    int hb, const int* __restrict__ row, const int* __restrict__ col,
    unsigned* __restrict__ ghist, int E, int nbrow, int colh)
{
    __shared__ unsigned lh[1280];
    const int tid = threadIdx.x;
    for (int i = tid; i < 1280; i += 256) lh[i] = 0;
    __syncthreads();
    const int per = (E + 191) / 192;
    const int e0 = hb * per;
    int e1 = e0 + per; if (e1 > E) e1 = E;
    for (int e = e0 + tid; e < e1; e += 256) {
        int r = row[e], c = col[e];
        int bin = ((c >= colh) ? nbrow : 0) + (r >> 4);
        atomicAdd(&lh[bin], 1u);
    }
    __syncthreads();
    const int nb = 2 * nbrow;
    for (int i = tid; i < nb; i += 256) {
        unsigned v = lh[i];
        if (v) atomicAdd(&ghist[i], v);
    }
}

__global__ __launch_bounds__(256, 2) void k_mid(
    const float* __restrict__ zd, const float* __restrict__ zs,
    const float* __restrict__ W1, const float* __restrict__ b1,
    _Float16* __restrict__ ud, _Float16* __restrict__ us,
    int ndrows, int nsrows, int ntd, int nbg,
    const int* __restrict__ row, const int* __restrict__ col,
    unsigned* __restrict__ ghist, int E, int nbrow, int colh)
{
    const int b = blockIdx.x;
    if (b < nbg) phase_gemm(b, zd, zs, W1, b1, ud, us, ndrows, nsrows, ntd);
    else         phase_hist(b - nbg, row, col, ghist, E, nbrow, colh);
}

// ------------------------------------------------------------------
// Phase B: one-block exclusive scan of ghist[nb] -> gcur (bin bases);
// gmeta[0] = n0 (class-0 record count = prefix at bin nbrow)
// ------------------------------------------------------------------
__global__ void k_scan(const unsigned* __restrict__ ghist, unsigned* __restrict__ gcur,
                       unsigned* __restrict__ gmeta, int nb, int nbrow)
{
    __shared__ unsigned tsum[256];
    const int tid = threadIdx.x;
    unsigned v[5];
    unsigned s = 0;
    #pragma unroll
    for (int i = 0; i < 5; ++i) {
        int idx = tid * 5 + i;
        v[i] = (idx < nb) ? ghist[idx] : 0u;
        s += v[i];
    }
    tsum[tid] = s;
    for (int off = 1; off < 256; off <<= 1) {
        __syncthreads();
        unsigned y = (tid >= off) ? tsum[tid - off] : 0u;
        __syncthreads();
        tsum[tid] += y;
    }
    __syncthreads();
    unsigned running = tsum[tid] - s;     // exclusive base for this thread's span
    #pragma unroll
    for (int i = 0; i < 5; ++i) {
        int idx = tid * 5 + i;
        if (idx < nb) {
            gcur[idx] = running;
            if (idx == nbrow) gmeta[0] = running;
            running += v[i];
        }
    }
}

// ------------------------------------------------------------------
// Phase C: LDS-ticketed scatter. rank = LDS atomicAdd return; bin base from
// one global atomicAdd per (block, nonzero bin). Records: row | col<<14 | eid<<32.
// Bucket-internal order is irrelevant (each edge computed independently, one
// writer per out[eid]).
// ------------------------------------------------------------------
__global__ __launch_bounds__(256, 4) void k_scatter(
    const int* __restrict__ row, const int* __restrict__ col,
    unsigned* __restrict__ gcur, unsigned long long* __restrict__ recbuf,
    int E, int nbrow, int colh)
{
    __shared__ unsigned lh[1280];
    const int tid = threadIdx.x;
    for (int i = tid; i < 1280; i += 256) lh[i] = 0;
    __syncthreads();

    const int per = E >> 9;               // E/512 = 2048
    const long base = (long)blockIdx.x * per;

    unsigned rnk[8], rcv[8];
    int binv[8];
    #pragma unroll
    for (int k = 0; k < 8; ++k) {
        long e = base + k * 256 + tid;    // coalesced
        int r = row[e], c = col[e];
        rcv[k] = (unsigned)r | ((unsigned)c << 14);
        binv[k] = ((c >= colh) ? nbrow : 0) + (r >> 4);
        rnk[k] = atomicAdd(&lh[binv[k]], 1u);
    }
    __syncthreads();
    const int nb = 2 * nbrow;
    for (int i = tid; i < nb; i += 256) {
        unsigned cnt = lh[i];
        if (cnt) lh[i] = atomicAdd(&gcur[i], cnt);   // count -> global base
    }
    __syncthreads();
    #pragma unroll
    for (int k = 0; k < 8; ++k) {
        long e = base + k * 256 + tid;
        unsigned pos = lh[binv[k]] + rnk[k];
        recbuf[pos] = (unsigned long long)rcv[k] | ((unsigned long long)(unsigned)e << 32);
    }
}

// ------------------------------------------------------------------
// Phase D: edge eval on bin-sorted records (R7-verified math + pipeline).
// Grid 1024 = 4 blocks/CU exactly co-resident; col-class cc = (b&7)>>2 pins each
// class's 1.92MB us slice to a 4-XCD group's L2s. ud reads walk 16-row bins
// (4-8KB sliding window) -> L1-resident. Records stream contiguously.
// ------------------------------------------------------------------
__global__ __launch_bounds__(256, 4) void k_edge(
    const _Float16* __restrict__ ud, const _Float16* __restrict__ us,
    const unsigned* __restrict__ gmeta, const unsigned long long* __restrict__ recbuf,
    const float* __restrict__ w2, const float* __restrict__ b2,
    float* __restrict__ out, int E)
{
    const int tid  = threadIdx.x;
    const int lane = tid & 63;
    const int wave = tid >> 6;
    const int le   = lane >> 3;          // edge slot 0..7
    const int q    = lane & 7;           // 16B sub-chunk 0..7
    const int lslot = wave * 8 + le;     // 0..31 within chunk

    const int b   = blockIdx.x;
    const int cc  = (b & 7) >> 2;
    const int sub = ((b >> 3) << 2) | (b & 3);    // 0..511
    const unsigned n0 = gmeta[0];
    const unsigned c0 = cc ? n0 : 0u;
    const unsigned nc = cc ? ((unsigned)E - n0) : n0;
    if (nc == 0) return;
    const unsigned K = (nc + 511u) >> 9;
    unsigned start = c0 + (unsigned)sub * K;
    unsigned climit = c0 + nc;
    if (start >= climit) return;
    unsigned end = start + K;
    if (end > climit) end = climit;

#if __has_builtin(__builtin_amdgcn_fdot2)
    half2v w2h[8];                       // w2[i*64 + q*8 + 2p .. +1]
    #pragma unroll
    for (int i = 0; i < 2; ++i)
        #pragma unroll
        for (int p = 0; p < 4; ++p) {
            half2v t;
            t[0] = (_Float16)w2[i * 64 + q * 8 + 2 * p];
            t[1] = (_Float16)w2[i * 64 + q * 8 + 2 * p + 1];
            w2h[i * 4 + p] = t;
        }
#else
    float w2r[16];
    #pragma unroll
    for (int i = 0; i < 2; ++i) {
        *reinterpret_cast<floatx4*>(&w2r[i * 8]) =
            *reinterpret_cast<const floatx4*>(&w2[i * 64 + q * 8]);
        *reinterpret_cast<floatx4*>(&w2r[i * 8 + 4]) =
            *reinterpret_cast<const floatx4*>(&w2[i * 64 + q * 8 + 4]);
    }
#endif
    const float b2v = b2[0];
    const int tend = (int)((end - start + 31u) >> 5);   // chunks of 32

#define LOADREC(RV, VV, tt)                                                    \
    {                                                                          \
        unsigned ei = start + (unsigned)(tt) * 32u + (unsigned)lslot;          \
        VV = ei < end;                                                         \
        RV = recbuf[VV ? ei : start];                                          \
    }

#define GATHER(D, RV)                                                          \
    {                                                                          \
        unsigned r = (unsigned)(RV) & 16383u;                                  \
        unsigned c = ((unsigned)(RV) >> 14) & 16383u;                          \
        const _Float16* up = ud + (size_t)r * 128 + q * 8;                     \
        const _Float16* vp = us + (size_t)c * 128 + q * 8;                     \
        D[0] = *reinterpret_cast<const half8*>(up);                            \
        D[1] = *reinterpret_cast<const half8*>(up + 64);                       \
        D[2] = *reinterpret_cast<const half8*>(vp);                            \
        D[3] = *reinterpret_cast<const half8*>(vp + 64);                       \
    }

#if __has_builtin(__builtin_amdgcn_fdot2)
#define DOTBODY(D, accv)                                                       \
    half8 s0 = D[0] + D[2];                                                    \
    s0 = __builtin_elementwise_max(s0, (half8)(_Float16)0.f);                  \
    half8 s1 = D[1] + D[3];                                                    \
    s1 = __builtin_elementwise_max(s1, (half8)(_Float16)0.f);                  \
    _Pragma("unroll")                                                          \
    for (int p = 0; p < 4; ++p) {                                              \
        half2v pr0; pr0[0] = s0[2 * p]; pr0[1] = s0[2 * p + 1];                \
        accv = __builtin_amdgcn_fdot2(pr0, w2h[p], accv, false);               \
        half2v pr1; pr1[0] = s1[2 * p]; pr1[1] = s1[2 * p + 1];                \
        accv = __builtin_amdgcn_fdot2(pr1, w2h[4 + p], accv, false);           \
    }
#else
#define DOTBODY(D, accv)                                                       \
    half8 s0 = D[0] + D[2];                                                    \
    s0 = __builtin_elementwise_max(s0, (half8)(_Float16)0.f);                  \
    half8 s1 = D[1] + D[3];                                                    \
    s1 = __builtin_elementwise_max(s1, (half8)(_Float16)0.f);                  \
    _Pragma("unroll")                                                          \
    for (int j = 0; j < 8; ++j) {                                              \
        accv += (float)s0[j] * w2r[j];                                         \
        accv += (float)s1[j] * w2r[8 + j];                                     \
    }
#endif

#define COMPUTE(D, RV, VV)                                                     \
    {                                                                          \
        float acc = 0.f;                                                       \
        DOTBODY(D, acc)                                                        \
        acc += __shfl_xor(acc, 1);                                             \
        acc += __shfl_xor(acc, 2);                                             \
        acc += __shfl_xor(acc, 4);                                             \
        if ((VV) && q == 0) out[(unsigned)((RV) >> 32)] = acc + b2v;           \
    }

    unsigned long long recA, recB = 0, recA2 = 0, recB2 = 0;
    bool vA, vB = false, vA2 = false, vB2 = false;
    int t = 0;
    LOADREC(recA, vA, 0)
    bool hasB = (1 < tend);
    if (hasB) LOADREC(recB, vB, 1)

    half8 dA[4], dB[4];
    while (true) {
        GATHER(dA, recA)
        if (hasB) GATHER(dB, recB)

        bool hasA2 = (t + 2 < tend), hasB2 = (t + 3 < tend);
        if (hasA2) LOADREC(recA2, vA2, t + 2)
        if (hasB2) LOADREC(recB2, vB2, t + 3)

        COMPUTE(dA, recA, vA)
        if (!hasB) break;
        COMPUTE(dB, recB, vB)

        if (!hasA2) break;
        recA = recA2; vA = vA2;
        recB = recB2; vB = vB2;
        hasB = hasB2;
        t += 2;
    }
#undef LOADREC
#undef GATHER
#undef DOTBODY
#undef COMPUTE
}

extern "C" void kernel_launch(void* const* d_in, const int* in_sizes, int n_in,
                              void* d_out, int out_size, void* d_ws, size_t ws_size,
                              hipStream_t stream) {
    const float* zd = (const float*)d_in[0];
    const float* zs = (const float*)d_in[1];
    const int*   row = (const int*)d_in[2];
    const int*   col = (const int*)d_in[3];
    const float* W1 = (const float*)d_in[4];
    const float* b1 = (const float*)d_in[5];
    const float* w2 = (const float*)d_in[6];
    const float* b2 = (const float*)d_in[7];
    float* out = (float*)d_out;

    const int nd = in_sizes[0];   // 10000*128
    const int ns = in_sizes[1];   // 15000*128
    const int E  = in_sizes[2];   // 1048576 (multiple of 512)
    const int ndrows = nd / 128;
    const int nsrows = ns / 128;
    const int nbrow = (ndrows + 15) >> 4;   // 625
    const int nb = 2 * nbrow;               // 1250 (<=1280)
    const int colh = nsrows >> 1;           // 7500

    // ws: ud fp16 | us fp16 | gmeta(16) ghist(1280) gcur(1280) | recbuf u64 E
    _Float16* ud = (_Float16*)d_ws;
    _Float16* us = ud + (size_t)ndrows * 128;
    size_t off = (size_t)((char*)(us + (size_t)nsrows * 128) - (char*)d_ws);
    off = (off + 63) & ~(size_t)63;
    unsigned* gmeta = (unsigned*)((char*)d_ws + off);
    unsigned* ghist = gmeta + 16;
    unsigned* gcur  = ghist + 1280;
    unsigned long long* recbuf =
        (unsigned long long*)(((uintptr_t)(gcur + 1280) + 63) & ~(uintptr_t)63);

    hipMemsetAsync(gmeta, 0, (16 + 1280) * sizeof(unsigned), stream);

    const int ntd = (ndrows + 63) / 64;   // 157
    const int nts = (nsrows + 63) / 64;   // 235
    const int nbg = ntd + nts;            // 392 GEMM blocks + 192 hist blocks
    hipLaunchKernelGGL(k_mid, dim3(nbg + 192), dim3(256), 0, stream,
                       zd, zs, W1, b1, ud, us, ndrows, nsrows, ntd, nbg,
                       row, col, ghist, E, nbrow, colh);

    hipLaunchKernelGGL(k_scan, dim3(1), dim3(256), 0, stream,
                       ghist, gcur, gmeta, nb, nbrow);

    hipLaunchKernelGGL(k_scatter, dim3(512), dim3(256), 0, stream,
                       row, col, gcur, recbuf, E, nbrow, colh);

    // exactly co-resident: 4 blocks/CU x 256 CUs
    hipLaunchKernelGGL(k_edge, dim3(1024), dim3(256), 0, stream,
                       ud, us, gmeta, recbuf, w2, b2, out, E);
}

// Round 10
// 142.993 us; speedup vs baseline: 1.0654x; 1.0654x over previous
//
#include <hip/hip_runtime.h>

typedef __attribute__((ext_vector_type(8))) short short8;
typedef __attribute__((ext_vector_type(4))) float floatx4;
typedef _Float16 half8 __attribute__((ext_vector_type(8)));
typedef _Float16 half4 __attribute__((ext_vector_type(4)));
typedef _Float16 half2v __attribute__((ext_vector_type(2)));

static __device__ __forceinline__ unsigned short f2bf(float x) {
    unsigned int u = __builtin_bit_cast(unsigned int, x);
    unsigned int r = (u + 0x7FFFu + ((u >> 16) & 1u)) >> 16;
    return (unsigned short)r;
}

// ------------------------------------------------------------------
// Phase A1: factorized GEMM (R6/R7-verified math):
//   ud[i] = zd[i] @ W1[0:128]  + 0.5*b1   (10000 x 128, fp16)
//   us[j] = zs[j] @ W1[128:256] + 0.5*b1  (15000 x 128, fp16)
// ------------------------------------------------------------------
static __device__ void phase_gemm(
    int b, const float* __restrict__ zd, const float* __restrict__ zs,
    const float* __restrict__ W1, const float* __restrict__ b1,
    _Float16* __restrict__ ud, _Float16* __restrict__ us,
    int ndrows, int nsrows, int ntd)
{
    const int tid  = threadIdx.x;
    const int lane = tid & 63;
    const int wave = tid >> 6;
    const int wh   = wave >> 1;
    const int we   = wave & 1;
    const int l15  = lane & 15;
    const int quad = lane >> 4;

    const bool isD = (b < ntd);
    const float* __restrict__ z = isD ? zd : zs;
    _Float16* __restrict__ u = isD ? ud : us;
    const int nrows = isD ? ndrows : nsrows;
    const int m0    = (isD ? b : b - ntd) * 64;
    const int koff0 = isD ? 0 : 128;
    const int whbase = wh * 64;

    short8 wfrag[16];
    #pragma unroll
    for (int s = 0; s < 4; ++s)
        #pragma unroll
        for (int mt = 0; mt < 4; ++mt) {
            short8 t;
            #pragma unroll
            for (int j = 0; j < 8; ++j)
                t[j] = (short)f2bf(
                    W1[(size_t)(koff0 + s * 32 + quad * 8 + j) * 128 +
                       whbase + mt * 16 + l15]);
            wfrag[s * 4 + mt] = t;
        }

    floatx4 acc[2][4];
    #pragma unroll
    for (int mt = 0; mt < 4; ++mt) {
        floatx4 bb = *reinterpret_cast<const floatx4*>(&b1[whbase + mt * 16 + quad * 4]);
        bb *= 0.5f;
        acc[0][mt] = bb;
        acc[1][mt] = bb;
    }

    int rowi[2], rowc[2];
    #pragma unroll
    for (int et = 0; et < 2; ++et) {
        rowi[et] = m0 + we * 32 + et * 16 + l15;
        rowc[et] = rowi[et] < nrows ? rowi[et] : nrows - 1;
    }

    #pragma unroll
    for (int s = 0; s < 4; ++s) {
        short8 bf[2];
        #pragma unroll
        for (int et = 0; et < 2; ++et) {
            const float* src = &z[(size_t)rowc[et] * 128 + s * 32 + quad * 8];
            floatx4 lo = *reinterpret_cast<const floatx4*>(src);
            floatx4 hi = *reinterpret_cast<const floatx4*>(src + 4);
            short8 t;
            t[0] = (short)f2bf(lo[0]); t[1] = (short)f2bf(lo[1]);
            t[2] = (short)f2bf(lo[2]); t[3] = (short)f2bf(lo[3]);
            t[4] = (short)f2bf(hi[0]); t[5] = (short)f2bf(hi[1]);
            t[6] = (short)f2bf(hi[2]); t[7] = (short)f2bf(hi[3]);
            bf[et] = t;
        }
        #pragma unroll
        for (int et = 0; et < 2; ++et)
            #pragma unroll
            for (int mt = 0; mt < 4; ++mt)
                acc[et][mt] = __builtin_amdgcn_mfma_f32_16x16x32_bf16(
                    wfrag[s * 4 + mt], bf[et], acc[et][mt], 0, 0, 0);
    }

    #pragma unroll
    for (int et = 0; et < 2; ++et) {
        if (rowi[et] < nrows) {
            #pragma unroll
            for (int mt = 0; mt < 4; ++mt) {
                half4 hv;
                #pragma unroll
                for (int rr = 0; rr < 4; ++rr) hv[rr] = (_Float16)acc[et][mt][rr];
                *reinterpret_cast<half4*>(
                    &u[(size_t)rowi[et] * 128 + whbase + mt * 16 + quad * 4]) = hv;
            }
        }
    }
}

// ------------------------------------------------------------------
// Phase A2: per-window self-contained scatter (NO global atomics, no init).
// Window sb = 2048 edges. bin = row >> 7 (128 drug rows per bin).
// Records grouped by bin inside the window region recbuf[sb*2048..] with an
// (nbins+1)-entry prefix header hdr[sb]. Bucket-internal order irrelevant:
// each record carries its edge id; out[eid] has exactly one writer.
// ------------------------------------------------------------------
static __device__ void phase_scatter(
    int sb, const int* __restrict__ row, const int* __restrict__ col,
    unsigned* __restrict__ hdr, unsigned long long* __restrict__ recbuf,
    int nbins, int hstride)
{
    __shared__ unsigned lcnt[160];
    __shared__ unsigned lbase[161];
    const int tid = threadIdx.x;
    for (int i = tid; i < nbins; i += 256) lcnt[i] = 0;
    __syncthreads();

    const long base = (long)sb * 2048;
    unsigned rnk[8], rcv[8];
    int binv[8];
    #pragma unroll
    for (int k = 0; k < 8; ++k) {
        long e = base + k * 256 + tid;    // coalesced
        int r = row[e], c = col[e];
        rcv[k] = (unsigned)r | ((unsigned)c << 14);
        binv[k] = r >> 7;
        rnk[k] = atomicAdd(&lcnt[binv[k]], 1u);
    }
    __syncthreads();
    if (tid == 0) {                        // serial prefix over <=160 bins: ~free
        unsigned run = 0;
        for (int i = 0; i < nbins; ++i) { lbase[i] = run; run += lcnt[i]; }
        lbase[nbins] = run;                // == 2048
    }
    __syncthreads();
    #pragma unroll
    for (int k = 0; k < 8; ++k) {
        long e = base + k * 256 + tid;
        unsigned pos = (unsigned)base + lbase[binv[k]] + rnk[k];
        recbuf[pos] = (unsigned long long)rcv[k] | ((unsigned long long)(unsigned)e << 32);
    }
    for (int i = tid; i <= nbins; i += 256) hdr[(size_t)sb * hstride + i] = lbase[i];
}

__global__ __launch_bounds__(256, 2) void k_mid(
    const float* __restrict__ zd, const float* __restrict__ zs,
    const float* __restrict__ W1, const float* __restrict__ b1,
    _Float16* __restrict__ ud, _Float16* __restrict__ us,
    int ndrows, int nsrows, int ntd, int nbg,
    const int* __restrict__ row, const int* __restrict__ col,
    unsigned* __restrict__ hdr, unsigned long long* __restrict__ recbuf,
    int nbins, int hstride)
{
    const int b = blockIdx.x;
    if (b < nbg) phase_gemm(b, zd, zs, W1, b1, ud, us, ndrows, nsrows, ntd);
    else         phase_scatter(b - nbg, row, col, hdr, recbuf, nbins, hstride);
}

// ------------------------------------------------------------------
// Phase B: edge eval, drug-row-binned. Block (bin, worker): stages the bin's
// 128-row ud slice (32KB) into LDS once -> u reads are LDS (conflict-free:
// bank = (rl*64 + q*4 + w) % 32 = (q*4 + w) % 32, so per wave-b128 each bank
// serves exactly 8 words = the minimum), eliminating the ud half of the L2
// gather. us (3.84MB) fits EVERY XCD's 4MiB L2 -> v gathers are L2-hits with
// no partitioning needed. L2 lines/edge: 8 -> ~4.3.
// 32KB LDS -> 4 blocks/CU, 16 waves/CU of TLP; 1-ahead header prefetch.
// ------------------------------------------------------------------
__global__ __launch_bounds__(256, 4) void k_edge(
    const _Float16* __restrict__ ud, const _Float16* __restrict__ us,
    const unsigned* __restrict__ hdr, const unsigned long long* __restrict__ recbuf,
    const float* __restrict__ w2, const float* __restrict__ b2,
    float* __restrict__ out, int ndrows, int nbins, int hstride, int nwin, int NW)
{
    __shared__ _Float16 uL[128 * 128];   // 32 KB: 128 rows x 128 fp16

    const int tid  = threadIdx.x;
    const int lane = tid & 63;
    const int wave = tid >> 6;
    const int le   = lane >> 3;          // edge slot 0..7
    const int q    = lane & 7;           // 16B sub-chunk 0..7
    const int lslot = wave * 8 + le;     // 0..31 within chunk

    const int b   = blockIdx.x;
    const int bin = b % nbins;
    const int w   = b / nbins;           // worker 0..NW-1

    // ---- stage ud slice for this bin ----
    const int r0 = bin << 7;
    int nr = ndrows - r0; if (nr > 128) nr = 128;
    for (int i = tid; i < nr * 16; i += 256) {
        int rr = i >> 4, pp = i & 15;
        *reinterpret_cast<half8*>(&uL[rr * 128 + pp * 8]) =
            *reinterpret_cast<const half8*>(&ud[(size_t)(r0 + rr) * 128 + pp * 8]);
    }

#if __has_builtin(__builtin_amdgcn_fdot2)
    half2v w2h[8];                       // w2[i*64 + q*8 + 2p .. +1]
    #pragma unroll
    for (int i = 0; i < 2; ++i)
        #pragma unroll
        for (int p = 0; p < 4; ++p) {
            half2v t;
            t[0] = (_Float16)w2[i * 64 + q * 8 + 2 * p];
            t[1] = (_Float16)w2[i * 64 + q * 8 + 2 * p + 1];
            w2h[i * 4 + p] = t;
        }
#else
    float w2r[16];
    #pragma unroll
    for (int i = 0; i < 2; ++i) {
        *reinterpret_cast<floatx4*>(&w2r[i * 8]) =
            *reinterpret_cast<const floatx4*>(&w2[i * 64 + q * 8]);
        *reinterpret_cast<floatx4*>(&w2r[i * 8 + 4]) =
            *reinterpret_cast<const floatx4*>(&w2[i * 64 + q * 8 + 4]);
    }
#endif
    const float b2v = b2[0];
    __syncthreads();

    int sb = w;
    if (sb >= nwin) return;
    unsigned h0 = hdr[(size_t)sb * hstride + bin];
    unsigned h1 = hdr[(size_t)sb * hstride + bin + 1];

    while (true) {
        // 1-ahead header prefetch (arrives under this window's compute)
        const int sbn = sb + NW;
        unsigned hn0 = 0, hn1 = 0;
        if (sbn < nwin) {
            hn0 = hdr[(size_t)sbn * hstride + bin];
            hn1 = hdr[(size_t)sbn * hstride + bin + 1];
        }

        const unsigned segbase = (unsigned)sb * 2048u + h0;
        const int seg = (int)(h1 - h0);

        for (int t0 = 0; t0 < seg; t0 += 32) {
            const int idx = t0 + lslot;
            const bool vld = idx < seg;
            const unsigned long long rec = recbuf[segbase + (vld ? idx : 0)];
            const unsigned rl = (unsigned)rec & 127u;            // row - bin*128
            const unsigned c  = ((unsigned)rec >> 14) & 16383u;

            // v: L2-resident us gather (2 lines per instr, coalesced per edge)
            const _Float16* vp = us + (size_t)c * 128 + q * 8;
            const half8 V0 = *reinterpret_cast<const half8*>(vp);
            const half8 V1 = *reinterpret_cast<const half8*>(vp + 64);
            // u: LDS
            const _Float16* up = &uL[rl * 128 + q * 8];
            const half8 U0 = *reinterpret_cast<const half8*>(up);
            const half8 U1 = *reinterpret_cast<const half8*>(up + 64);

            float acc = 0.f;
            half8 s0 = U0 + V0;
            s0 = __builtin_elementwise_max(s0, (half8)(_Float16)0.f);
            half8 s1 = U1 + V1;
            s1 = __builtin_elementwise_max(s1, (half8)(_Float16)0.f);
#if __has_builtin(__builtin_amdgcn_fdot2)
            #pragma unroll
            for (int p = 0; p < 4; ++p) {
                half2v pr0; pr0[0] = s0[2 * p]; pr0[1] = s0[2 * p + 1];
                acc = __builtin_amdgcn_fdot2(pr0, w2h[p], acc, false);
                half2v pr1; pr1[0] = s1[2 * p]; pr1[1] = s1[2 * p + 1];
                acc = __builtin_amdgcn_fdot2(pr1, w2h[4 + p], acc, false);
            }
#else
            #pragma unroll
            for (int j = 0; j < 8; ++j) {
                acc += (float)s0[j] * w2r[j];
                acc += (float)s1[j] * w2r[8 + j];
            }
#endif
            acc += __shfl_xor(acc, 1);
            acc += __shfl_xor(acc, 2);
            acc += __shfl_xor(acc, 4);
            if (vld && q == 0) out[(unsigned)(rec >> 32)] = acc + b2v;
        }

        if (sbn >= nwin) break;
        sb = sbn; h0 = hn0; h1 = hn1;
    }
}

extern "C" void kernel_launch(void* const* d_in, const int* in_sizes, int n_in,
                              void* d_out, int out_size, void* d_ws, size_t ws_size,
                              hipStream_t stream) {
    const float* zd = (const float*)d_in[0];
    const float* zs = (const float*)d_in[1];
    const int*   row = (const int*)d_in[2];
    const int*   col = (const int*)d_in[3];
    const float* W1 = (const float*)d_in[4];
    const float* b1 = (const float*)d_in[5];
    const float* w2 = (const float*)d_in[6];
    const float* b2 = (const float*)d_in[7];
    float* out = (float*)d_out;

    const int nd = in_sizes[0];   // 10000*128
    const int ns = in_sizes[1];   // 15000*128
    const int E  = in_sizes[2];   // 1048576 (multiple of 2048)
    const int ndrows = nd / 128;
    const int nsrows = ns / 128;

    const int nbins   = (ndrows + 127) >> 7;   // 79 bins of 128 drug rows
    const int hstride = nbins + 1;             // 80
    const int nwin    = E / 2048;              // 512 windows

    // ws: ud fp16 | us fp16 | hdr u32 [nwin][hstride] | recbuf u64 [E]
    _Float16* ud = (_Float16*)d_ws;
    _Float16* us = ud + (size_t)ndrows * 128;
    size_t off = (size_t)((char*)(us + (size_t)nsrows * 128) - (char*)d_ws);
    off = (off + 63) & ~(size_t)63;
    unsigned* hdr = (unsigned*)((char*)d_ws + off);
    unsigned long long* recbuf = (unsigned long long*)
        (((uintptr_t)(hdr + (size_t)nwin * hstride) + 63) & ~(uintptr_t)63);

    const int ntd = (ndrows + 63) / 64;   // 157
    const int nts = (nsrows + 63) / 64;   // 235
    const int nbg = ntd + nts;            // 392 GEMM blocks, then 512 scatter blocks
    hipLaunchKernelGGL(k_mid, dim3(nbg + nwin), dim3(256), 0, stream,
                       zd, zs, W1, b1, ud, us, ndrows, nsrows, ntd, nbg,
                       row, col, hdr, recbuf, nbins, hstride);

    const int NW = 12;                    // workers per bin -> 948 blocks (~3.7/CU)
    hipLaunchKernelGGL(k_edge, dim3(nbins * NW), dim3(256), 0, stream,
                       ud, us, hdr, recbuf, w2, b2, out,
                       ndrows, nbins, hstride, nwin, NW);
}